// Round 2
// baseline (515.349 us; speedup 1.0000x reference)
//
#include <hip/hip_runtime.h>

typedef unsigned short u16;
typedef unsigned int u32;
typedef __attribute__((ext_vector_type(8))) short short8;
typedef __attribute__((ext_vector_type(4))) float float4_;
typedef __attribute__((ext_vector_type(4))) unsigned short ushort4_;
typedef __attribute__((ext_vector_type(4))) unsigned int u32x4;

// ---------- bf16 helpers ----------
__device__ __forceinline__ u16 f2bf(float v) {          // RNE
    u32 x = __float_as_uint(v);
    return (u16)((x + 0x7fffu + ((x >> 16) & 1u)) >> 16);
}
__device__ __forceinline__ float bf2f(u16 h) {
    return __uint_as_float(((u32)h) << 16);
}

// ---------- async global->LDS, 16B/lane ----------
__device__ __forceinline__ void gl16(const u16* g, u16* l) {
    __builtin_amdgcn_global_load_lds(
        (const __attribute__((address_space(1))) void*)g,
        (__attribute__((address_space(3))) void*)l, 16, 0, 0);
}
__device__ __forceinline__ void gl16f(const float* g, float* l) {
    __builtin_amdgcn_global_load_lds(
        (const __attribute__((address_space(1))) void*)g,
        (__attribute__((address_space(3))) void*)l, 16, 0, 0);
}

#define Bsz 8
#define Tsz 4096
#define Csz 512
#define Usz 512
#define NG  1536           // 3U
#define KK  1024           // 2 taps * C
#define MM  32768          // B*T
#define NCH 64             // scan chunks
#define CHL 64             // chunk length

// Dekker-style truncation split of two fp32 (as u32) into packed bf16 hi / bf16 lo.
// hi = top 16 bits (exact trunc); lo = v - hi (exact in fp32), then truncated to bf16.
// Captured precision: rel err <= 2^-14 per element.
__device__ __forceinline__ void splitpair(u32 u0, u32 u1, u32& hp, u32& lp) {
    u32 m1 = u1 & 0xffff0000u;
    hp = (u0 >> 16) | m1;
    float l0 = __uint_as_float(u0) - __uint_as_float(u0 & 0xffff0000u);
    float l1 = __uint_as_float(u1) - __uint_as_float(m1);
    lp = (__float_as_uint(l0) >> 16) | (__float_as_uint(l1) & 0xffff0000u);
}

// ---------- P: weights [K=1024][N=1536] fp32 -> transposed bf16 hi/lo [N][K]; + zero page ----------
__global__ void prep_k(const float* __restrict__ kern, u16* __restrict__ KTh,
                       u16* __restrict__ KTl, float* __restrict__ zpage) {
    int idx = blockIdx.x * 256 + threadIdx.x;   // n*1024 + k
    if (idx < Csz) zpage[idx] = 0.0f;
    if (idx >= NG * KK) return;
    int k = idx & 1023;
    int n = idx >> 10;
    float v = kern[(size_t)k * NG + n];
    u16 h = f2bf(v);
    KTh[idx] = h;
    KTl[idx] = f2bf(v - bf2f(h));
}

// ---------- GEMM: gates = A'*K' (3-pass bf16 split, A split in-register) ----------
// A' row m = concat(in[b,t], in[b,t+1]) with in[b,T]=0 (zero page redirect).
// Epilogue: X=bf16(tanh(g0)) -> Xb, F=sigmoid(g1) fp32 -> Fp, O=sigmoid(g2) fp32 -> d_out.
__global__ __launch_bounds__(256, 2) void gemm_gates(
    const float* __restrict__ Ain, const float* __restrict__ zpage,
    const u16* __restrict__ Bh, const u16* __restrict__ Bl,
    const float* __restrict__ bias,
    u16* __restrict__ X, float* __restrict__ F, float* __restrict__ O)
{
    // A tile stored as two k-halves [2][128 rows][16 floats] (64B row stride -> milder LDS
    // bank aliasing than 128B stride), B^T tiles row-major [128][32] u16.
    __shared__ float lA[2 * 128 * 16];
    __shared__ u16 lBh[128 * 32], lBl[128 * 32];

    const int tid  = threadIdx.x;
    const int lane = tid & 63;
    const int wave = tid >> 6;
    const int m0 = blockIdx.x * 128;
    const int n0 = blockIdx.y * 128;
    const int b  = m0 >> 12;            // 128 | 4096 -> block never straddles batches
    const int t0 = m0 & 4095;
    const int bbase = b << 12;          // b*4096

    float4_ acc[4][4];
    #pragma unroll
    for (int i = 0; i < 4; ++i)
        #pragma unroll
        for (int j = 0; j < 4; ++j) acc[i][j] = (float4_)0.0f;

    const int wm = (wave >> 1) * 64;
    const int wn = (wave & 1) * 64;
    const int ar = wm + (lane & 15);
    const int br = wn + (lane & 15);
    const int kq = (lane >> 4) * 8;     // 0,8,16,24
    const int hh = kq >> 4;             // A k-half
    const int kq15 = kq & 15;

    for (int kc = 0; kc < KK; kc += 32) {
        __syncthreads();   // protect LDS from previous iteration's readers
        const int tap = kc >> 9;
        const int kin = kc & 511;
        const int trow = t0 + tap;
        // --- A staging: fp32 tile 128x32 = 16KB, 4 gl16 iters ---
        #pragma unroll
        for (int it = 0; it < 4; ++it) {
            const int s = it * 256 + tid;          // chunk in [0,1024)
            const int ah = s >> 9;                 // k-half
            const int sh = s & 511;
            const int row = sh >> 2;
            const int cp = sh & 3;
            const int col = kin + ah * 16 + cp * 4;
            const int t = trow + row;
            const float* gp = (t <= 4095)
                ? (Ain + (((size_t)(bbase + t)) << 9) + col)
                : (zpage + col);                   // zero-pad row t==4096
            gl16f(gp, lA + (size_t)(s - lane) * 4);
        }
        // --- B staging: hi/lo bf16 tiles 128x32 = 8KB each, 2 gl16 iters each ---
        #pragma unroll
        for (int it = 0; it < 2; ++it) {
            const int s = it * 256 + tid;
            const int row = s >> 2, cp = s & 3;
            const size_t boff = (((size_t)(n0 + row)) << 10) + kc + cp * 8;
            const int ldso = (s - lane) * 8;
            gl16(Bh + boff, lBh + ldso);
            gl16(Bl + boff, lBl + ldso);
        }
        __syncthreads();   // staging complete (vmcnt(0) drained by barrier)

        short8 fah[4], fal[4], fbh[4], fbl[4];
        #pragma unroll
        for (int i = 0; i < 4; ++i) {
            const float* ap = lA + hh * 2048 + (ar + i * 16) * 16 + kq15;
            u32x4 a = *(const u32x4*)ap;
            u32x4 c = *(const u32x4*)(ap + 4);
            union { u32 u[4]; short8 s8; } hi, lo;
            splitpair(a.x, a.y, hi.u[0], lo.u[0]);
            splitpair(a.z, a.w, hi.u[1], lo.u[1]);
            splitpair(c.x, c.y, hi.u[2], lo.u[2]);
            splitpair(c.z, c.w, hi.u[3], lo.u[3]);
            fah[i] = hi.s8; fal[i] = lo.s8;
            fbh[i] = *(const short8*)(lBh + (br + i * 16) * 32 + kq);
            fbl[i] = *(const short8*)(lBl + (br + i * 16) * 32 + kq);
        }
        #pragma unroll
        for (int mi = 0; mi < 4; ++mi)
            #pragma unroll
            for (int ni = 0; ni < 4; ++ni) {
                acc[mi][ni] = __builtin_amdgcn_mfma_f32_16x16x32_bf16(fah[mi], fbh[ni], acc[mi][ni], 0, 0, 0);
                acc[mi][ni] = __builtin_amdgcn_mfma_f32_16x16x32_bf16(fal[mi], fbh[ni], acc[mi][ni], 0, 0, 0);
                acc[mi][ni] = __builtin_amdgcn_mfma_f32_16x16x32_bf16(fah[mi], fbl[ni], acc[mi][ni], 0, 0, 0);
            }
    }

    // epilogue: bias + activation. Plane uniform per block (128 | 512).
    const int plane = blockIdx.y >> 2;   // 0=X,1=F,2=O
    const int rq = (lane >> 4) * 4;
    const int cl = lane & 15;
    #pragma unroll
    for (int mi = 0; mi < 4; ++mi)
        #pragma unroll
        for (int ni = 0; ni < 4; ++ni) {
            const int gm = m0 + wm + mi * 16 + rq;
            const int gn = n0 + wn + ni * 16 + cl;
            const float bv = bias[gn];
            const int cp = gn & 511;
            #pragma unroll
            for (int r = 0; r < 4; ++r) {
                float v = acc[mi][ni][r] + bv;
                if (plane == 0) {
                    float res = 1.0f - 2.0f / (__expf(2.0f * v) + 1.0f);   // tanh, overflow-safe
                    X[(size_t)(gm + r) * Usz + cp] = f2bf(res);
                } else {
                    float res = 1.0f / (1.0f + __expf(-v));                // sigmoid, overflow-safe
                    float* dst = (plane == 1) ? F : O;
                    dst[(size_t)(gm + r) * Usz + cp] = res;
                }
            }
        }
}

// ---------- S1: per-chunk composites A=prod f, B=chunk applied to c=0 ----------
__global__ void scan_chunk(const float* __restrict__ F, const u16* __restrict__ X,
                           float* __restrict__ CA, float* __restrict__ CB) {
    int g = blockIdx.x * 256 + threadIdx.x;     // 65536 = B*NCH*U/4
    int u4 = (g & 127) * 4;
    int bc = g >> 7;                             // b*NCH + ch
    size_t base = (size_t)bc * CHL * Usz + u4;
    float4_ c = (float4_)0.0f, A = (float4_)1.0f;
    for (int i = 0; i < CHL; ++i) {
        float4_ fv = *(const float4_*)(F + base + (size_t)i * Usz);
        ushort4_ xr = *(const ushort4_*)(X + base + (size_t)i * Usz);
        float4_ xv;
        #pragma unroll
        for (int j = 0; j < 4; ++j) xv[j] = bf2f(xr[j]);
        c = fv * c + (1.0f - fv) * xv;
        A = A * fv;
    }
    *(float4_*)(CA + (size_t)bc * Usz + u4) = A;
    *(float4_*)(CB + (size_t)bc * Usz + u4) = c;
}

// ---------- S2: sequential prefix across chunks -> chunk-start carries ----------
__global__ void scan_prefix(const float* __restrict__ CA, const float* __restrict__ CB,
                            float* __restrict__ CS) {
    int g = blockIdx.x * 256 + threadIdx.x;     // 4096 = B*U
    int u = g & 511;
    int b = g >> 9;
    float c = 0.0f;
    for (int ch = 0; ch < NCH; ++ch) {
        int idx = (b * NCH + ch) * Usz + u;
        CS[idx] = c;
        c = CA[idx] * c + CB[idx];
    }
}

// ---------- S3: re-scan chunks with carry, h = sigmoid(o)*c (O in-place in out) ----------
__global__ void scan_final(const float* __restrict__ F, const u16* __restrict__ X,
                           const float* __restrict__ CS, float* __restrict__ out) {
    int g = blockIdx.x * 256 + threadIdx.x;     // 65536
    int u4 = (g & 127) * 4;
    int bc = g >> 7;
    size_t base = (size_t)bc * CHL * Usz + u4;
    float4_ c = *(const float4_*)(CS + (size_t)bc * Usz + u4);
    for (int i = 0; i < CHL; ++i) {
        float4_ fv = *(const float4_*)(F + base + (size_t)i * Usz);
        ushort4_ xr = *(const ushort4_*)(X + base + (size_t)i * Usz);
        float4_ xv;
        #pragma unroll
        for (int j = 0; j < 4; ++j) xv[j] = bf2f(xr[j]);
        c = fv * c + (1.0f - fv) * xv;
        float4_ ov = *(const float4_*)(out + base + (size_t)i * Usz);  // read O before overwrite
        *(float4_*)(out + base + (size_t)i * Usz) = ov * c;
    }
}

extern "C" void kernel_launch(void* const* d_in, const int* in_sizes, int n_in,
                              void* d_out, int out_size, void* d_ws, size_t ws_size,
                              hipStream_t stream) {
    const float* in   = (const float*)d_in[0];   // [8,4096,512] fp32
    const float* kern = (const float*)d_in[1];   // [2,512,1536] fp32
    const float* bias = (const float*)d_in[2];   // [1536] fp32
    float* out = (float*)d_out;                  // [8,4096,512] fp32
    char* ws = (char*)d_ws;

    // workspace layout (~105 MB)
    const size_t KT_B   = (size_t)NG * KK * sizeof(u16);       //  3,145,728
    const size_t OFF_KTl   = KT_B;                             //  3,145,728
    const size_t OFF_ZP    = 2 * KT_B;                         //  6,291,456
    const size_t OFF_F     = OFF_ZP + 2048;                    //  6,293,504
    const size_t OFF_X     = OFF_F + (size_t)MM * Usz * 4;     // 73,402,368
    const size_t OFF_CA    = OFF_X + (size_t)MM * Usz * 2;     // 106,956,800
    const size_t CH_B      = (size_t)Bsz * NCH * Usz * 4;      //  1,048,576
    const size_t NEED      = OFF_CA + 3 * CH_B;                // 110,102,528

    if (ws_size < NEED) return;   // diagnostic guard: fail-with-poison instead of OOB fault

    u16*   KTh = (u16*)ws;
    u16*   KTl = (u16*)(ws + OFF_KTl);
    float* zp  = (float*)(ws + OFF_ZP);
    float* F   = (float*)(ws + OFF_F);
    u16*   Xb  = (u16*)(ws + OFF_X);
    float* CA  = (float*)(ws + OFF_CA);
    float* CB  = CA + CH_B / 4;
    float* CS  = CB + CH_B / 4;

    prep_k<<<NG * KK / 256, 256, 0, stream>>>(kern, KTh, KTl, zp);
    gemm_gates<<<dim3(MM / 128, NG / 128), 256, 0, stream>>>(in, zp, KTh, KTl, bias, Xb, F, out);
    scan_chunk<<<Bsz * NCH * Usz / 4 / 256, 256, 0, stream>>>(F, Xb, CA, CB);
    scan_prefix<<<Bsz * Usz / 256, 256, 0, stream>>>(CA, CB, CS);
    scan_final<<<Bsz * NCH * Usz / 4 / 256, 256, 0, stream>>>(F, Xb, CS, out);
}

// Round 4
// 374.917 us; speedup vs baseline: 1.3746x; 1.3746x over previous
//
#include <hip/hip_runtime.h>

typedef unsigned short u16;
typedef unsigned int u32;
typedef _Float16 f16;
typedef __attribute__((ext_vector_type(8))) _Float16 half8;
typedef __attribute__((ext_vector_type(2))) __fp16 fp16x2;
typedef __attribute__((ext_vector_type(4))) float float4_;
typedef __attribute__((ext_vector_type(4))) unsigned short ushort4_;

union hu { f16 h; u16 u; };

__device__ __forceinline__ u32 pkrtz(float a, float b) {
    fp16x2 t = __builtin_amdgcn_cvt_pkrtz(a, b);
    union { fp16x2 h; u32 u; } cv; cv.h = t;
    return cv.u;
}

// ---------- async global->LDS, 16B/lane ----------
__device__ __forceinline__ void gl16(const u16* g, u16* l) {
    __builtin_amdgcn_global_load_lds(
        (const __attribute__((address_space(1))) void*)g,
        (__attribute__((address_space(3))) void*)l, 16, 0, 0);
}
__device__ __forceinline__ void gl16f(const float* g, float* l) {
    __builtin_amdgcn_global_load_lds(
        (const __attribute__((address_space(1))) void*)g,
        (__attribute__((address_space(3))) void*)l, 16, 0, 0);
}

#define Bsz 8
#define Tsz 4096
#define Csz 512
#define Usz 512
#define NG  1536           // 3U
#define KK  1024           // 2 taps * C
#define MM  32768          // B*T
#define NCH 64             // scan chunks
#define CHL 64             // chunk length

// ---------- P: weights [K=1024][N=1536] fp32 -> transposed fp16 [N][K]; + zero page ----------
__global__ void prep_k(const float* __restrict__ kern, u16* __restrict__ KTh,
                       float* __restrict__ zpage) {
    int n = blockIdx.x * 256 + threadIdx.x;
    int k = blockIdx.y;
    if (k == 0 && n < Csz) zpage[n] = 0.0f;
    float v = kern[(size_t)k * NG + n];
    hu cv; cv.h = (f16)v;                 // RNE
    KTh[(size_t)n * KK + k] = cv.u;
}

// ---------- GEMM: gates = A'*K' single-pass fp16 MFMA ----------
// A' row m = concat(in[b,t], in[b,t+1]) with in[b,T]=0 (zero page redirect).
// Epilogue: X=fp16(tanh(g0)), F=sigmoid(g1) fp32, O=sigmoid(g2) fp32 -> d_out.
__global__ __launch_bounds__(256, 3) void gemm_gates(
    const float* __restrict__ Ain, const float* __restrict__ zpage,
    const u16* __restrict__ Bh, const float* __restrict__ bias,
    u16* __restrict__ X, float* __restrict__ F, float* __restrict__ O)
{
    // A tile: two 16-float k-halves, half-stride 2052 (=2048+4) so the 4 read quads
    // hit disjoint bank sets. B^T tile row-major [128][32] fp16.
    __shared__ float lA[4104];
    __shared__ u16 lBh[128 * 32];

    const int tid  = threadIdx.x;
    const int lane = tid & 63;
    const int wave = tid >> 6;

    // swizzle: 12 n-blocks consecutive (share one A tile), 16 m-blocks per group
    const int g   = blockIdx.x;
    const int grp = g / 192;
    const int r   = g - grp * 192;
    const int nb  = r % 12;
    const int mb  = grp * 16 + r / 12;
    const int m0 = mb * 128;
    const int n0 = nb * 128;
    const int b  = m0 >> 12;            // 128 | 4096 -> block never straddles batches
    const int t0 = m0 & 4095;
    const int bbase = b << 12;          // b*4096

    float4_ acc[4][4];
    #pragma unroll
    for (int i = 0; i < 4; ++i)
        #pragma unroll
        for (int j = 0; j < 4; ++j) acc[i][j] = (float4_)0.0f;

    const int wm = (wave >> 1) * 64;
    const int wn = (wave & 1) * 64;
    const int ar = wm + (lane & 15);
    const int br = wn + (lane & 15);
    const int kq = (lane >> 4) * 8;     // 0,8,16,24
    const int hh = kq >> 4;             // A k-half
    const int kq15 = kq & 15;

    for (int kc = 0; kc < KK; kc += 32) {
        __syncthreads();   // protect LDS from previous iteration's readers
        const int tap = kc >> 9;
        const int kin = kc & 511;
        const int trow = t0 + tap;
        // --- A staging: fp32 tile 2x[128][16] = 16KB, 4 gl16 iters ---
        #pragma unroll
        for (int it = 0; it < 4; ++it) {
            const int s = it * 256 + tid;          // [0,1024)
            const int ah = s >> 9;                 // k-half
            const int sh = s & 511;
            const int row = sh >> 2;
            const int cp = sh & 3;
            const int col = kin + ah * 16 + cp * 4;
            const int t = trow + row;
            const float* gp = (t <= 4095)
                ? (Ain + (((size_t)(bbase + t)) << 9) + col)
                : (zpage + col);                   // zero-pad row t==4096
            const int S = s - lane;                // wave-uniform
            gl16f(gp, lA + (S >> 9) * 2052 + (S & 511) * 4);
        }
        // --- B staging: fp16 tile 128x32 = 8KB, 2 gl16 iters ---
        #pragma unroll
        for (int it = 0; it < 2; ++it) {
            const int s = it * 256 + tid;
            const int row = s >> 2, cp = s & 3;
            const size_t boff = (((size_t)(n0 + row)) << 10) + kc + cp * 8;
            gl16(Bh + boff, lBh + (s - lane) * 8);
        }
        __syncthreads();   // staging complete (barrier drains vmcnt)

        half8 fah[4], fbh[4];
        #pragma unroll
        for (int i = 0; i < 4; ++i) {
            const float* ap = lA + hh * 2052 + (ar + i * 16) * 16 + kq15;
            float4_ a0 = *(const float4_*)ap;
            float4_ a1 = *(const float4_*)(ap + 4);
            union { u32 u[4]; half8 h8; } pa;
            pa.u[0] = pkrtz(a0.x, a0.y);
            pa.u[1] = pkrtz(a0.z, a0.w);
            pa.u[2] = pkrtz(a1.x, a1.y);
            pa.u[3] = pkrtz(a1.z, a1.w);
            fah[i] = pa.h8;
            fbh[i] = *(const half8*)(lBh + (br + i * 16) * 32 + kq);
        }
        #pragma unroll
        for (int mi = 0; mi < 4; ++mi)
            #pragma unroll
            for (int ni = 0; ni < 4; ++ni)
                acc[mi][ni] = __builtin_amdgcn_mfma_f32_16x16x32_f16(fah[mi], fbh[ni], acc[mi][ni], 0, 0, 0);
    }

    // epilogue: bias + activation. Plane uniform per block (128 | 512).
    const int plane = nb >> 2;   // 0=X,1=F,2=O
    const int rq = (lane >> 4) * 4;
    const int cl = lane & 15;
    #pragma unroll
    for (int mi = 0; mi < 4; ++mi)
        #pragma unroll
        for (int ni = 0; ni < 4; ++ni) {
            const int gm = m0 + wm + mi * 16 + rq;
            const int gn = n0 + wn + ni * 16 + cl;
            const float bv = bias[gn];
            const int cp = gn & 511;
            #pragma unroll
            for (int r2 = 0; r2 < 4; ++r2) {
                float v = acc[mi][ni][r2] + bv;
                if (plane == 0) {
                    float res = 1.0f - 2.0f / (__expf(2.0f * v) + 1.0f);   // tanh, overflow-safe
                    hu cv; cv.h = (f16)res;                                 // RNE fp16
                    X[(size_t)(gm + r2) * Usz + cp] = cv.u;
                } else {
                    float res = 1.0f / (1.0f + __expf(-v));                // sigmoid, overflow-safe
                    float* dst = (plane == 1) ? F : O;
                    dst[(size_t)(gm + r2) * Usz + cp] = res;
                }
            }
        }
}

__device__ __forceinline__ float4_ x4(const u16* p) {
    ushort4_ xr = *(const ushort4_*)p;
    float4_ xv;
    #pragma unroll
    for (int j = 0; j < 4; ++j) { hu cv; cv.u = xr[j]; xv[j] = (float)cv.h; }
    return xv;
}

// ---------- S1: per-chunk composites A=prod f, B=chunk applied to c=0 ----------
__global__ void scan_chunk(const float* __restrict__ F, const u16* __restrict__ X,
                           float* __restrict__ CA, float* __restrict__ CB) {
    int g = blockIdx.x * 256 + threadIdx.x;     // 65536 = B*NCH*U/4
    int u4 = (g & 127) * 4;
    int bc = g >> 7;                             // b*NCH + ch
    size_t base = (size_t)bc * CHL * Usz + u4;
    float4_ c = (float4_)0.0f, A = (float4_)1.0f;
    for (int i = 0; i < CHL; ++i) {
        float4_ fv = *(const float4_*)(F + base + (size_t)i * Usz);
        float4_ xv = x4(X + base + (size_t)i * Usz);
        c = fv * c + (1.0f - fv) * xv;
        A = A * fv;
    }
    *(float4_*)(CA + (size_t)bc * Usz + u4) = A;
    *(float4_*)(CB + (size_t)bc * Usz + u4) = c;
}

// ---------- S2: sequential prefix across chunks -> chunk-start carries ----------
__global__ void scan_prefix(const float* __restrict__ CA, const float* __restrict__ CB,
                            float* __restrict__ CS) {
    int g = blockIdx.x * 256 + threadIdx.x;     // 4096 = B*U
    int u = g & 511;
    int b = g >> 9;
    float c = 0.0f;
    for (int ch = 0; ch < NCH; ++ch) {
        int idx = (b * NCH + ch) * Usz + u;
        CS[idx] = c;
        c = CA[idx] * c + CB[idx];
    }
}

// ---------- S3: re-scan chunks with carry, h = sigmoid(o)*c (O in-place in out) ----------
__global__ void scan_final(const float* __restrict__ F, const u16* __restrict__ X,
                           const float* __restrict__ CS, float* __restrict__ out) {
    int g = blockIdx.x * 256 + threadIdx.x;     // 65536
    int u4 = (g & 127) * 4;
    int bc = g >> 7;
    size_t base = (size_t)bc * CHL * Usz + u4;
    float4_ c = *(const float4_*)(CS + (size_t)bc * Usz + u4);
    for (int i = 0; i < CHL; ++i) {
        float4_ fv = *(const float4_*)(F + base + (size_t)i * Usz);
        float4_ xv = x4(X + base + (size_t)i * Usz);
        c = fv * c + (1.0f - fv) * xv;
        float4_ ov = *(const float4_*)(out + base + (size_t)i * Usz);  // read O before overwrite
        *(float4_*)(out + base + (size_t)i * Usz) = ov * c;
    }
}

extern "C" void kernel_launch(void* const* d_in, const int* in_sizes, int n_in,
                              void* d_out, int out_size, void* d_ws, size_t ws_size,
                              hipStream_t stream) {
    const float* in   = (const float*)d_in[0];   // [8,4096,512] fp32
    const float* kern = (const float*)d_in[1];   // [2,512,1536] fp32
    const float* bias = (const float*)d_in[2];   // [1536] fp32
    float* out = (float*)d_out;                  // [8,4096,512] fp32
    char* ws = (char*)d_ws;

    // workspace layout (~107 MB; known budget >= 110,102,528 from R2 pass)
    const size_t KT_B   = (size_t)NG * KK * sizeof(u16);       //  3,145,728
    const size_t OFF_ZP = KT_B;
    const size_t OFF_F  = OFF_ZP + 2048;                       //  3,147,776
    const size_t OFF_X  = OFF_F + (size_t)MM * Usz * 4;        // 70,256,640
    const size_t OFF_CA = OFF_X + (size_t)MM * Usz * 2;        // 103,811,072
    const size_t CH_B   = (size_t)Bsz * NCH * Usz * 4;         //  1,048,576
    const size_t NEED   = OFF_CA + 3 * CH_B;                   // 106,956,800

    if (ws_size < NEED) return;   // guard: fail-with-poison instead of OOB fault

    u16*   KTh = (u16*)ws;
    float* zp  = (float*)(ws + OFF_ZP);
    float* F   = (float*)(ws + OFF_F);
    u16*   Xb  = (u16*)(ws + OFF_X);
    float* CA  = (float*)(ws + OFF_CA);
    float* CB  = CA + CH_B / 4;
    float* CS  = CB + CH_B / 4;

    prep_k<<<dim3(NG / 256, KK), 256, 0, stream>>>(kern, KTh, zp);
    gemm_gates<<<(MM / 128) * (NG / 128), 256, 0, stream>>>(in, zp, KTh, bias, Xb, F, out);
    scan_chunk<<<Bsz * NCH * Usz / 4 / 256, 256, 0, stream>>>(F, Xb, CA, CB);
    scan_prefix<<<Bsz * Usz / 256, 256, 0, stream>>>(CA, CB, CS);
    scan_final<<<Bsz * NCH * Usz / 4 / 256, 256, 0, stream>>>(F, Xb, CS, out);
}

// Round 5
// 323.061 us; speedup vs baseline: 1.5952x; 1.1605x over previous
//
#include <hip/hip_runtime.h>

typedef unsigned short u16;
typedef unsigned int u32;
typedef _Float16 f16;
typedef __attribute__((ext_vector_type(8))) _Float16 half8;
typedef __attribute__((ext_vector_type(2))) __fp16 fp16x2;
typedef __attribute__((ext_vector_type(4))) float float4_;
typedef __attribute__((ext_vector_type(4))) unsigned short ushort4_;
typedef __attribute__((ext_vector_type(4))) unsigned int u32x4;

union hu { f16 h; u16 u; };

__device__ __forceinline__ u32 pkrtz(float a, float b) {
    fp16x2 t = __builtin_amdgcn_cvt_pkrtz(a, b);
    union { fp16x2 h; u32 u; } cv; cv.h = t;
    return cv.u;
}

// ---------- async global->LDS, 16B/lane ----------
__device__ __forceinline__ void gl16(const u16* g, u16* l) {
    __builtin_amdgcn_global_load_lds(
        (const __attribute__((address_space(1))) void*)g,
        (__attribute__((address_space(3))) void*)l, 16, 0, 0);
}

#define Bsz 8
#define Tsz 4096
#define Csz 512
#define Usz 512
#define NG  1536           // 3U
#define KK  1024           // 2 taps * C
#define MM  32768          // B*T
#define NCH 64             // scan chunks
#define CHL 64             // chunk length

// ---------- P0: inputs fp32 -> fp16 plane [8][4097][512], zero row at t=4096 ----------
__global__ void prep_a(const float* __restrict__ in, u16* __restrict__ A16) {
    int gid = blockIdx.x * 256 + threadIdx.x;       // 2,097,664 threads, 8 halves each
    int idx8 = gid * 8;
    int c8 = idx8 & 511;
    int row = idx8 >> 9;                            // b*4097 + t
    int b = (u32)row / 4097u;
    int t = row - b * 4097;
    u32x4 w;
    if (t == Tsz) {
        w = (u32x4)0;
    } else {
        const float* p = in + ((size_t)(b * Tsz + t) << 9) + c8;
        float4_ v0 = *(const float4_*)p;
        float4_ v1 = *(const float4_*)(p + 4);
        w.x = pkrtz(v0.x, v0.y); w.y = pkrtz(v0.z, v0.w);
        w.z = pkrtz(v1.x, v1.y); w.w = pkrtz(v1.z, v1.w);
    }
    *(u32x4*)(A16 + idx8) = w;
}

// ---------- P1: weights [K=1024][N=1536] fp32 -> transposed fp16 [N][K] ----------
__global__ void prep_k(const float* __restrict__ kern, u16* __restrict__ KT) {
    int n = blockIdx.x * 256 + threadIdx.x;
    int k = blockIdx.y;
    float v = kern[(size_t)k * NG + n];
    hu cv; cv.h = (f16)v;                 // RNE
    KT[(size_t)n * KK + k] = cv.u;
}

// ---------- GEMM: gates = A'*K', fp16 MFMA, BK=64, XOR-swizzled LDS ----------
// A' row m = concat(A16[b][t], A16[b][t+1]) (zero row materialized in prep_a).
// Epilogue: X=fp16(tanh(g0)), F=fp16(sigmoid(g1)), O=sigmoid(g2) fp32 -> d_out.
__global__ __launch_bounds__(256, 4) void gemm_gates(
    const u16* __restrict__ A16, const u16* __restrict__ KT,
    const float* __restrict__ bias,
    u16* __restrict__ X, u16* __restrict__ F, float* __restrict__ O)
{
    // Tiles [128 rows][64 halves]; 16B chunk c of row r stored at position c ^ (r&7)
    // -> every ds_read_b128 hits the 8-words/bank wave64 floor.
    __shared__ u16 lA[8192], lB[8192];

    const int tid  = threadIdx.x;
    const int lane = tid & 63;
    const int wave = tid >> 6;

    // swizzle: 12 n-blocks consecutive (share one A tile), 16 m-blocks per group
    const int g   = blockIdx.x;
    const int grp = g / 192;
    const int r   = g - grp * 192;
    const int nb  = r % 12;
    const int mb  = grp * 16 + r / 12;
    const int m0 = mb * 128;
    const int n0 = nb * 128;
    const int b  = m0 >> 12;            // 128 | 4096 -> block never straddles batches
    const int t0 = m0 & 4095;
    const int arow0 = b * (Tsz + 1) + t0;

    float4_ acc[4][4];
    #pragma unroll
    for (int i = 0; i < 4; ++i)
        #pragma unroll
        for (int j = 0; j < 4; ++j) acc[i][j] = (float4_)0.0f;

    const int wm = (wave >> 1) * 64;
    const int wn = (wave & 1) * 64;
    const int ar = wm + (lane & 15);
    const int br = wn + (lane & 15);
    const int q  = lane >> 4;           // k-quad
    const int swz = lane & 7;           // == ar&7 == br&7 (wm,wn multiples of 64)

    for (int kc = 0; kc < KK; kc += 64) {
        __syncthreads();   // protect LDS from previous iteration's readers
        const int tap = kc >> 9;
        const int kin = kc & 511;
        const int ab = arow0 + tap;
        // --- A staging: 128x64 fp16 = 16KB, 4 gl16 iters, XOR-permuted source ---
        #pragma unroll
        for (int it = 0; it < 4; ++it) {
            const int s = it * 256 + tid;          // chunk slot [0,1024)
            const int row = s >> 3, p = s & 7;
            const int c = p ^ (row & 7);
            gl16(A16 + (((size_t)(ab + row)) << 9) + kin + c * 8, lA + (s - lane) * 8);
        }
        // --- B staging: 128x64 fp16 = 16KB ---
        #pragma unroll
        for (int it = 0; it < 4; ++it) {
            const int s = it * 256 + tid;
            const int row = s >> 3, p = s & 7;
            const int c = p ^ (row & 7);
            gl16(KT + (((size_t)(n0 + row)) << 10) + kc + c * 8, lB + (s - lane) * 8);
        }
        __syncthreads();   // staging complete (barrier drains vmcnt)

        #pragma unroll
        for (int s2 = 0; s2 < 2; ++s2) {
            half8 fa[4], fb[4];
            const int cc = (s2 * 4 + q) ^ swz;     // swizzled chunk position
            #pragma unroll
            for (int i = 0; i < 4; ++i) {
                fa[i] = *(const half8*)(lA + (ar + i * 16) * 64 + cc * 8);
                fb[i] = *(const half8*)(lB + (br + i * 16) * 64 + cc * 8);
            }
            #pragma unroll
            for (int mi = 0; mi < 4; ++mi)
                #pragma unroll
                for (int ni = 0; ni < 4; ++ni)
                    acc[mi][ni] = __builtin_amdgcn_mfma_f32_16x16x32_f16(fa[mi], fb[ni], acc[mi][ni], 0, 0, 0);
        }
    }

    // epilogue: bias + activation. Plane uniform per block (128 | 512).
    const int plane = nb >> 2;   // 0=X,1=F,2=O
    const int rq = q * 4;
    const int cl = lane & 15;
    #pragma unroll
    for (int mi = 0; mi < 4; ++mi)
        #pragma unroll
        for (int ni = 0; ni < 4; ++ni) {
            const int gm = m0 + wm + mi * 16 + rq;
            const int gn = n0 + wn + ni * 16 + cl;
            const float bv = bias[gn];
            const int cp = gn & 511;
            #pragma unroll
            for (int r2 = 0; r2 < 4; ++r2) {
                float v = acc[mi][ni][r2] + bv;
                if (plane == 0) {
                    float res = 1.0f - 2.0f / (__expf(2.0f * v) + 1.0f);   // tanh, overflow-safe
                    hu cv; cv.h = (f16)res;
                    X[(size_t)(gm + r2) * Usz + cp] = cv.u;
                } else if (plane == 1) {
                    float res = 1.0f / (1.0f + __expf(-v));                // sigmoid, overflow-safe
                    hu cv; cv.h = (f16)res;
                    F[(size_t)(gm + r2) * Usz + cp] = cv.u;
                } else {
                    float res = 1.0f / (1.0f + __expf(-v));
                    O[(size_t)(gm + r2) * Usz + cp] = res;
                }
            }
        }
}

__device__ __forceinline__ float4_ x4(const u16* p) {
    ushort4_ xr = *(const ushort4_*)p;
    float4_ xv;
    #pragma unroll
    for (int j = 0; j < 4; ++j) { hu cv; cv.u = xr[j]; xv[j] = (float)cv.h; }
    return xv;
}

// ---------- S1: per-chunk composites A=prod f, B=chunk applied to c=0 ----------
__global__ void scan_chunk(const u16* __restrict__ F, const u16* __restrict__ X,
                           float* __restrict__ CA, float* __restrict__ CB) {
    int g = blockIdx.x * 256 + threadIdx.x;     // 65536 = B*NCH*U/4
    int u4 = (g & 127) * 4;
    int bc = g >> 7;                             // b*NCH + ch
    size_t base = (size_t)bc * CHL * Usz + u4;
    float4_ c = (float4_)0.0f, A = (float4_)1.0f;
    for (int i = 0; i < CHL; ++i) {
        float4_ fv = x4(F + base + (size_t)i * Usz);
        float4_ xv = x4(X + base + (size_t)i * Usz);
        c = fv * c + (1.0f - fv) * xv;
        A = A * fv;
    }
    *(float4_*)(CA + (size_t)bc * Usz + u4) = A;
    *(float4_*)(CB + (size_t)bc * Usz + u4) = c;
}

// ---------- S2: sequential prefix across chunks -> chunk-start carries ----------
__global__ void scan_prefix(const float* __restrict__ CA, const float* __restrict__ CB,
                            float* __restrict__ CS) {
    int g = blockIdx.x * 256 + threadIdx.x;     // 4096 = B*U
    int u = g & 511;
    int b = g >> 9;
    float c = 0.0f;
    #pragma unroll 16
    for (int ch = 0; ch < NCH; ++ch) {
        int idx = (b * NCH + ch) * Usz + u;
        CS[idx] = c;
        c = CA[idx] * c + CB[idx];
    }
}

// ---------- S3: re-scan chunks with carry, h = sigmoid(o)*c (O in-place in out) ----------
__global__ void scan_final(const u16* __restrict__ F, const u16* __restrict__ X,
                           const float* __restrict__ CS, float* __restrict__ out) {
    int g = blockIdx.x * 256 + threadIdx.x;     // 65536
    int u4 = (g & 127) * 4;
    int bc = g >> 7;
    size_t base = (size_t)bc * CHL * Usz + u4;
    float4_ c = *(const float4_*)(CS + (size_t)bc * Usz + u4);
    for (int i = 0; i < CHL; ++i) {
        float4_ fv = x4(F + base + (size_t)i * Usz);
        float4_ xv = x4(X + base + (size_t)i * Usz);
        c = fv * c + (1.0f - fv) * xv;
        float4_ ov = *(const float4_*)(out + base + (size_t)i * Usz);  // read O before overwrite
        *(float4_*)(out + base + (size_t)i * Usz) = ov * c;
    }
}

extern "C" void kernel_launch(void* const* d_in, const int* in_sizes, int n_in,
                              void* d_out, int out_size, void* d_ws, size_t ws_size,
                              hipStream_t stream) {
    const float* in   = (const float*)d_in[0];   // [8,4096,512] fp32
    const float* kern = (const float*)d_in[1];   // [2,512,1536] fp32
    const float* bias = (const float*)d_in[2];   // [1536] fp32
    float* out = (float*)d_out;                  // [8,4096,512] fp32
    char* ws = (char*)d_ws;

    // workspace layout (~102 MB; known budget >= 110,102,528 from R2 pass)
    const size_t A16_B  = (size_t)Bsz * (Tsz + 1) * Csz * 2;   // 33,562,624
    const size_t OFF_KT = A16_B;
    const size_t OFF_F  = OFF_KT + (size_t)NG * KK * 2;        // 36,708,352
    const size_t OFF_X  = OFF_F + (size_t)MM * Usz * 2;        // 70,262,784
    const size_t OFF_CA = OFF_X + (size_t)MM * Usz * 2;        // 103,817,216
    const size_t CH_B   = (size_t)Bsz * NCH * Usz * 4;         //  1,048,576
    const size_t NEED   = OFF_CA + 3 * CH_B;                   // 106,962,944

    if (ws_size < NEED) return;   // guard: fail-with-poison instead of OOB fault

    u16*   A16 = (u16*)ws;
    u16*   KT  = (u16*)(ws + OFF_KT);
    u16*   Fh  = (u16*)(ws + OFF_F);
    u16*   Xb  = (u16*)(ws + OFF_X);
    float* CA  = (float*)(ws + OFF_CA);
    float* CB  = CA + CH_B / 4;
    float* CS  = CB + CH_B / 4;

    prep_a<<<(int)(A16_B / 16 / 256), 256, 0, stream>>>(in, A16);
    prep_k<<<dim3(NG / 256, KK), 256, 0, stream>>>(kern, KT);
    gemm_gates<<<(MM / 128) * (NG / 128), 256, 0, stream>>>(A16, KT, bias, Xb, Fh, out);
    scan_chunk<<<Bsz * NCH * Usz / 4 / 256, 256, 0, stream>>>(Fh, Xb, CA, CB);
    scan_prefix<<<Bsz * Usz / 256, 256, 0, stream>>>(CA, CB, CS);
    scan_final<<<Bsz * NCH * Usz / 4 / 256, 256, 0, stream>>>(Fh, Xb, CS, out);
}